// Round 3
// baseline (1671.706 us; speedup 1.0000x reference)
//
#include <hip/hip_runtime.h>
#include <hip/hip_bf16.h>

#define B_SZ 512
#define T_SZ 512
#define D_SZ 256
#define H_SZ 200
#define G4   800   // 4*H
#define NSUB 50    // gate subtiles of 16
#define BS   8     // steps per LDS staging block
#define WROW 800   // bytes per Wout row (200 floats)
#define WAT  216   // wA row stride in shorts (bank-spread: 2-way max)

typedef __attribute__((ext_vector_type(8))) short short8;
typedef __attribute__((ext_vector_type(4))) short short4v;
typedef __attribute__((ext_vector_type(4))) float f32x4;

__device__ __forceinline__ unsigned short f2bf(float x) {
    unsigned u = __builtin_bit_cast(unsigned, x);
    unsigned r = (u + 0x7FFFu + ((u >> 16) & 1u)) >> 16;
    return (unsigned short)r;
}
__device__ __forceinline__ float sigm(float v) { return 1.f / (1.f + __expf(-v)); }

__device__ __forceinline__ void gl_lds16(const void* g, void* l) {
    __builtin_amdgcn_global_load_lds(
        (const __attribute__((address_space(1))) unsigned int*)g,
        (__attribute__((address_space(3))) unsigned int*)l, 16, 0, 0);
}

// ---------------------------------------------------------------------------
// Kernel 0: fp32 -> bf16 conversion (x)
// ---------------------------------------------------------------------------
__global__ __launch_bounds__(256)
void cvt_bf16(const float* __restrict__ src, unsigned short* __restrict__ dst, int n4)
{
    int i = blockIdx.x * 256 + threadIdx.x;
    const int stride = gridDim.x * 256;
    for (; i < n4; i += stride) {
        float4 v = ((const float4*)src)[i];
        unsigned a = (unsigned)f2bf(v.x) | ((unsigned)f2bf(v.y) << 16);
        unsigned b = (unsigned)f2bf(v.z) | ((unsigned)f2bf(v.w) << 16);
        ((uint2*)dst)[i] = make_uint2(a, b);
    }
}

// ---------------------------------------------------------------------------
// Kernel 0b: W_ih fp32 -> bf16 with gate-row interleave.
// New row r = unit*4 + gate  sources old row  (r&3)*200 + (r>>2).
// ---------------------------------------------------------------------------
__global__ __launch_bounds__(256)
void cvt_w_perm(const float* __restrict__ Wih, unsigned short* __restrict__ dst)
{
    int i = blockIdx.x * 256 + threadIdx.x;     // over 800*64 float4 chunks
    if (i >= G4 * (D_SZ / 4)) return;
    const int r = i >> 6, ch = i & 63;
    const int p = (r & 3) * H_SZ + (r >> 2);
    float4 v = ((const float4*)(Wih + (size_t)p * D_SZ))[ch];
    unsigned a = (unsigned)f2bf(v.x) | ((unsigned)f2bf(v.y) << 16);
    unsigned b = (unsigned)f2bf(v.z) | ((unsigned)f2bf(v.w) << 16);
    ((uint2*)dst)[i] = make_uint2(a, b);
}

// ---------------------------------------------------------------------------
// Kernel 0c: permuted bias sum (b_ih+b_hh) + padded Wout copy (for the
// wave-uniform 1 KiB global_load_lds row stage).
// ---------------------------------------------------------------------------
__global__ __launch_bounds__(256)
void prep(const float* __restrict__ bih, const float* __restrict__ bhh,
          const float* __restrict__ Wout, float* __restrict__ bsum,
          float* __restrict__ wpad)
{
    const int i = blockIdx.x * 256 + threadIdx.x;
    if (i < G4) {
        const int p = (i & 3) * H_SZ + (i >> 2);
        bsum[i] = bih[p] + bhh[p];
    }
    if (i < T_SZ * H_SZ + 256)
        wpad[i] = (i < T_SZ * H_SZ) ? Wout[i] : 0.f;
}

// ---------------------------------------------------------------------------
// Kernel 1: pre = x@W_ih^T + bsum, bf16 MFMA (rows already gate-interleaved)
// output layout pre[tt][S(50)][q(4)][b(512)][i(4)] bf16  (g = S*16 + q*4 + i)
// ---------------------------------------------------------------------------
__global__ __launch_bounds__(256)
void pre_gemm(const unsigned short* __restrict__ xbf,
              const unsigned short* __restrict__ wbf,
              const float* __restrict__ bs,
              unsigned short* __restrict__ pre, int t0)
{
    const int tt = blockIdx.x;
    const int t  = t0 + tt;
    const int b0 = blockIdx.y * 64;
    const int g0 = blockIdx.z * 256;

    __shared__ unsigned short Al[256 * 32];
    __shared__ unsigned short Bl[64 * 32];

    const int tid  = threadIdx.x;
    const int w    = tid >> 6;
    const int lane = tid & 63;
    const int col  = lane & 15, q = lane >> 4;

    f32x4 acc[4][4];
    #pragma unroll
    for (int i = 0; i < 4; ++i)
        #pragma unroll
        for (int j = 0; j < 4; ++j) acc[i][j] = (f32x4)0.f;

    const int arow = w * 64 + (lane >> 2);
    const int akoff = (lane & 3) * 8;
    const int brow = b0 + w * 16 + (lane >> 2);

    for (int kc = 0; kc < 8; ++kc) {
        const int d0 = kc * 32;
        if (kc) __syncthreads();
        #pragma unroll
        for (int j = 0; j < 4; ++j) {
            int g = g0 + arow + j * 16;
            if (g > G4 - 1) g = G4 - 1;
            gl_lds16(wbf + (size_t)g * D_SZ + d0 + akoff,
                     (void*)(Al + (w * 64 + j * 16) * 32));
        }
        gl_lds16(xbf + ((size_t)brow * T_SZ + t) * D_SZ + d0 + akoff,
                 (void*)(Bl + (w * 16) * 32));
        __syncthreads();

        short8 af[4], bv[4];
        #pragma unroll
        for (int s = 0; s < 4; ++s)
            af[s] = *(const short8*)&Al[(w * 64 + s * 16 + col) * 32 + q * 8];
        #pragma unroll
        for (int s = 0; s < 4; ++s)
            bv[s] = *(const short8*)&Bl[(s * 16 + col) * 32 + q * 8];
        #pragma unroll
        for (int gs = 0; gs < 4; ++gs)
            #pragma unroll
            for (int bsi = 0; bsi < 4; ++bsi)
                acc[gs][bsi] = __builtin_amdgcn_mfma_f32_16x16x32_bf16(af[gs], bv[bsi], acc[gs][bsi], 0, 0, 0);
    }

    #pragma unroll
    for (int gs = 0; gs < 4; ++gs) {
        const int S = blockIdx.z * 16 + w * 4 + gs;
        if (S < NSUB) {
            const int gq = S * 16 + q * 4;
            const float4 bi = *(const float4*)&bs[gq];
            #pragma unroll
            for (int bsi = 0; bsi < 4; ++bsi) {
                f32x4 a = acc[gs][bsi];
                unsigned lo = (unsigned)f2bf(a[0] + bi.x) |
                              ((unsigned)f2bf(a[1] + bi.y) << 16);
                unsigned hi = (unsigned)f2bf(a[2] + bi.z) |
                              ((unsigned)f2bf(a[3] + bi.w) << 16);
                const size_t idx = (((size_t)tt * NSUB + S) * 4 + q) * 512 + (b0 + bsi * 16 + col);
                ((uint2*)pre)[idx] = make_uint2(lo, hi);
            }
        }
    }
}

// ---------------------------------------------------------------------------
// Kernel 2: LSTM recurrence. 256 WGs x 512 thr (8 waves); 2 batches per WG.
// Gate rows interleaved (r = unit*4 + gate): each MFMA output lane holds all
// 4 gates of one hidden unit -> fully in-register elementwise.
// Register-pressure fix (round 3): each wave keeps only FIVE W_hh tiles in
// registers (tiles wv*5..wv*5+4, ~130 regs); tiles 40..49 live in LDS (wA)
// and are read per step via ds_read_b128.  Wave wv also computes LDS tile
// 40+wv; waves 0,1 additionally compute tiles 48,49.  No tile overlap.
// Wout rows staged per BLOCK (wave wv stages row blk*8+wv) -> no per-step
// vmcnt.  Steps 0..6 of each block use an lgkmcnt-only barrier (staging
// loads stay in flight); step 7 uses full __syncthreads() (vmcnt drain).
// ---------------------------------------------------------------------------
__global__ __launch_bounds__(512, 2)
void lstm_rec(const unsigned short* __restrict__ pre,  // [ct][50][4][512][4] bf16 (permuted rows)
              const float* __restrict__ Whh,           // original [4H][H] fp32
              const float* __restrict__ wpad,          // padded Wout copy [512*200 + 256]
              const float* __restrict__ bout,
              float* __restrict__ state,               // h,c,oa each [512][200]
              float* __restrict__ out,
              int t0, int C_T)
{
    const int bk = blockIdx.x;
    const int cidx = (bk >> 3) + (bk & 7) * 32;   // XCD swizzle
    const int b0 = cidx * 2;

    const int tid = threadIdx.x, lane = tid & 63, wv = tid >> 6;
    const int col = lane & 15, q = lane >> 4;

    __shared__ __align__(16) unsigned short preS[2 * BS * 1600]; // 51.2 KB
    __shared__ __align__(16) unsigned short wA[10 * 16 * WAT];   // 69.1 KB
    // hT: buf0 rows at [0,512), buf1 at [512,1024), scrap [1024,1600)
    __shared__ __align__(16) short hT[1600];                     // 3.2 KB
    __shared__ __align__(16) float woutS[2 * BS * 256];          // 16.4 KB
    __shared__ float redbuf[16];

    const int c7 = col & 7;
    const int bsel = col >> 3;                           // batch this lane finishes
    const int rbase = bsel * 256;                        // B-operand read base

    // lane ownership: c7<5 -> reg tile wv*5+c7; c7==5 -> LDS tile 40+wv;
    // c7==6 (waves 0,1 only) -> LDS tile 48+wv.  c7==7 invalid.
    const int own = (c7 < 5) ? (wv * 5 + c7) : ((c7 == 5) ? (40 + wv) : (48 + (wv & 1)));
    const bool valid = (c7 < 6) || (c7 == 6 && wv < 2);
    const int usel = own * 4 + q;                        // hidden unit
    const int hw_base = valid ? (bsel * 256 + usel) : (1024 + lane);
    const int jsel = (c7 < 7) ? c7 : 6;

    int pofs[7];
    #pragma unroll
    for (int j = 0; j < 5; ++j)
        pofs[j] = ((wv * 5 + j) * 4 + q) * 8 + bsel * 4;
    pofs[5] = ((40 + wv) * 4 + q) * 8 + bsel * 4;
    pofs[6] = ((48 + (wv & 1)) * 4 + q) * 8 + bsel * 4;

    // ---- fill wA: LDS-resident W_hh tiles 40..49 (bf16, row stride WAT) ----
    for (int idx = tid; idx < 10 * 16 * 50; idx += 512) {   // float4 chunks
        const int L = idx / 800;
        const int rem = idx - L * 800;
        const int r = rem / 50;
        const int kq = rem - r * 50;
        const int gp = (40 + L) * 16 + r;
        const float4 f = *(const float4*)(Whh + (size_t)((gp & 3) * H_SZ + (gp >> 2)) * H_SZ + kq * 4);
        unsigned lo = (unsigned)f2bf(f.x) | ((unsigned)f2bf(f.y) << 16);
        unsigned hi = (unsigned)f2bf(f.z) | ((unsigned)f2bf(f.w) << 16);
        *(uint2*)(wA + (size_t)L * 16 * WAT + r * WAT + kq * 4) = make_uint2(lo, hi);
    }
    // zero the 16-short row pad (read by the K-tail for q>=2)
    for (int idx = tid; idx < 160 * 16; idx += 512) {
        const int row = idx >> 4;
        wA[row * WAT + 200 + (idx & 15)] = 0;
    }

    // ---- W_hh reg fragments: 5 tiles/wave (tiles wv*5 .. wv*5+4) ----
    short8 aw[5][6];
#if __has_builtin(__builtin_amdgcn_mfma_f32_16x16x16bf16_1k)
    short4v aw6[5];
#else
    short8 aw6[5];
#endif
    #pragma unroll
    for (int j = 0; j < 5; ++j) {
        const int gp = (wv * 5 + j) * 16 + col;                 // permuted row
        const float* wr = Whh + (size_t)((gp & 3) * H_SZ + (gp >> 2)) * H_SZ;
        #pragma unroll
        for (int kc = 0; kc < 6; ++kc) {
            const int k = kc * 32 + q * 8;
            float4 f0 = *(const float4*)(wr + k);
            float4 f1 = *(const float4*)(wr + k + 4);
            short8 s;
            s[0] = (short)f2bf(f0.x); s[1] = (short)f2bf(f0.y);
            s[2] = (short)f2bf(f0.z); s[3] = (short)f2bf(f0.w);
            s[4] = (short)f2bf(f1.x); s[5] = (short)f2bf(f1.y);
            s[6] = (short)f2bf(f1.z); s[7] = (short)f2bf(f1.w);
            aw[j][kc] = s;
        }
#if __has_builtin(__builtin_amdgcn_mfma_f32_16x16x16bf16_1k)
        short4v t4 = (short4v)0;
        if (q < 2) {
            float4 f = *(const float4*)(wr + 192 + q * 4);
            t4[0] = (short)f2bf(f.x); t4[1] = (short)f2bf(f.y);
            t4[2] = (short)f2bf(f.z); t4[3] = (short)f2bf(f.w);
        }
        aw6[j] = t4;
#else
        short8 t8 = (short8)0;
        if (q == 0) {
            float4 f0 = *(const float4*)(wr + 192);
            float4 f1 = *(const float4*)(wr + 196);
            t8[0] = (short)f2bf(f0.x); t8[1] = (short)f2bf(f0.y);
            t8[2] = (short)f2bf(f0.z); t8[3] = (short)f2bf(f0.w);
            t8[4] = (short)f2bf(f1.x); t8[5] = (short)f2bf(f1.y);
            t8[6] = (short)f2bf(f1.z); t8[7] = (short)f2bf(f1.w);
        }
        aw6[j] = t8;
#endif
    }

    // LDS A-operand pointers for this wave's LDS tiles
    const unsigned short* wA5  = wA + (size_t)wv * 16 * WAT + col * WAT + q * 8;
    const unsigned short* wA6  = wA + (size_t)(8 + (wv & 1)) * 16 * WAT + col * WAT + q * 8;
    const unsigned short* wA5t = wA + (size_t)wv * 16 * WAT + col * WAT + 192 + q * 4;
    const unsigned short* wA6t = wA + (size_t)(8 + (wv & 1)) * 16 * WAT + col * WAT + 192 + q * 4;

    float* h_st  = state;
    float* c_st  = state + (size_t)B_SZ * H_SZ;
    float* oa_st = state + (size_t)2 * B_SZ * H_SZ;

    // ---- init hT (buf0 = h state or zeros; buf1 + scrap + k>=200 zeros) ----
    for (int i = tid; i < 1600; i += 512) {
        short v = 0;
        if (t0 > 0 && i < 512) {
            const int r = i >> 8, u = i & 255;
            if (u < H_SZ) v = (short)f2bf(h_st[(size_t)(b0 + r) * H_SZ + u]);
        }
        hT[i] = v;
    }

    // ---- per-lane cell state (scalar: one (unit,batch) per lane) ----
    float c_v = 0.f, oa_v = 0.f;
    if (t0 > 0 && valid) {
        c_v  = c_st [(size_t)(b0 + bsel) * H_SZ + usel];
        oa_v = oa_st[(size_t)(b0 + bsel) * H_SZ + usel];
    }

    const int nblk = C_T / BS;
    const char* preb = (const char*)pre;

    // ---- stage block 0 (pre + Wout rows t0..t0+7) ----
    {
        const char* src = preb + ((size_t)wv * 200) * 4096 + (size_t)b0 * 8;
        unsigned short* dst = preS + (0 * BS + wv) * 1600;
        gl_lds16(src + (size_t)lane * 4096,         dst);
        gl_lds16(src + (size_t)(lane + 64) * 4096,  dst + 512);
        gl_lds16(src + (size_t)(lane + 128) * 4096, dst + 1024);
        gl_lds16(src + (size_t)(lane + 136) * 4096, dst + 1088);
        gl_lds16((const char*)wpad + (size_t)(t0 + wv) * WROW + lane * 16,
                 (void*)(woutS + wv * 256));
    }
    __syncthreads();

    for (int blk = 0; blk < nblk; ++blk) {
        const int bn = blk & 1;
        // stage next block (clamped) into other buffers
        {
            const int nb = (blk + 1 < nblk) ? blk + 1 : blk;
            const char* src = preb + ((size_t)(nb * BS + wv) * 200) * 4096 + (size_t)b0 * 8;
            unsigned short* dst = preS + ((bn ^ 1) * BS + wv) * 1600;
            gl_lds16(src + (size_t)lane * 4096,         dst);
            gl_lds16(src + (size_t)(lane + 64) * 4096,  dst + 512);
            gl_lds16(src + (size_t)(lane + 128) * 4096, dst + 1024);
            gl_lds16(src + (size_t)(lane + 136) * 4096, dst + 1088);
            gl_lds16((const char*)wpad + (size_t)(t0 + nb * BS + wv) * WROW + lane * 16,
                     (void*)(woutS + ((bn ^ 1) * BS + wv) * 256));
        }
        const unsigned short* psb = preS + bn * (BS * 1600);

        for (int s = 0; s < BS; ++s) {
            const int tc = blk * BS + s;
            const unsigned short* ps = psb + s * 1600;
            const short* hrow = hT + ((tc & 1) << 9) + rbase;

            // acc init from staged pre (bf16 -> f32)
            f32x4 acc[7];
            #pragma unroll
            for (int j = 0; j < 7; ++j) {
                const uint2 p = *(const uint2*)(ps + pofs[j]);
                f32x4 a;
                a[0] = __builtin_bit_cast(float, p.x << 16);
                a[1] = __builtin_bit_cast(float, p.x & 0xFFFF0000u);
                a[2] = __builtin_bit_cast(float, p.y << 16);
                a[3] = __builtin_bit_cast(float, p.y & 0xFFFF0000u);
                acc[j] = a;
            }
            // MFMA: acc += Whh * h  (5 reg tiles + 1-2 LDS tiles)
            #pragma unroll
            for (int kc = 0; kc < 6; ++kc) {
                const short8 bf = *(const short8*)(hrow + kc * 32 + q * 8);
                const short8 a5 = *(const short8*)(wA5 + kc * 32);
                #pragma unroll
                for (int j = 0; j < 5; ++j)
                    acc[j] = __builtin_amdgcn_mfma_f32_16x16x32_bf16(aw[j][kc], bf, acc[j], 0, 0, 0);
                acc[5] = __builtin_amdgcn_mfma_f32_16x16x32_bf16(a5, bf, acc[5], 0, 0, 0);
                if (wv < 2) {
                    const short8 a6 = *(const short8*)(wA6 + kc * 32);
                    acc[6] = __builtin_amdgcn_mfma_f32_16x16x32_bf16(a6, bf, acc[6], 0, 0, 0);
                }
            }
#if __has_builtin(__builtin_amdgcn_mfma_f32_16x16x16bf16_1k)
            {
                const short4v bt = *(const short4v*)(hrow + 192 + q * 4);
                #pragma unroll
                for (int j = 0; j < 5; ++j)
                    acc[j] = __builtin_amdgcn_mfma_f32_16x16x16bf16_1k(aw6[j], bt, acc[j], 0, 0, 0);
                const short4v a5t = *(const short4v*)wA5t;
                acc[5] = __builtin_amdgcn_mfma_f32_16x16x16bf16_1k(a5t, bt, acc[5], 0, 0, 0);
                if (wv < 2) {
                    const short4v a6t = *(const short4v*)wA6t;
                    acc[6] = __builtin_amdgcn_mfma_f32_16x16x16bf16_1k(a6t, bt, acc[6], 0, 0, 0);
                }
            }
#else
            {
                const short8 bt = *(const short8*)(hrow + 192 + q * 8);
                #pragma unroll
                for (int j = 0; j < 5; ++j)
                    acc[j] = __builtin_amdgcn_mfma_f32_16x16x32_bf16(aw6[j], bt, acc[j], 0, 0, 0);
                short8 a5t = (q == 0) ? *(const short8*)(wA5t) : (short8)0;
                acc[5] = __builtin_amdgcn_mfma_f32_16x16x32_bf16(a5t, bt, acc[5], 0, 0, 0);
                if (wv < 2) {
                    short8 a6t = (q == 0) ? *(const short8*)(wA6t) : (short8)0;
                    acc[6] = __builtin_amdgcn_mfma_f32_16x16x32_bf16(a6t, bt, acc[6], 0, 0, 0);
                }
            }
#endif
            // in-register elementwise: this lane finishes tile jsel
            f32x4 sel = acc[0];
            #pragma unroll
            for (int j = 1; j < 7; ++j)
                if (jsel == j) sel = acc[j];

            const float gi = sigm(sel[0]);
            const float gf = sigm(sel[1]);
            const float gg = 2.f * sigm(2.f * sel[2]) - 1.f;
            const float go = sigm(sel[3]);
            const float cn = gf * c_v + gi * gg;
            c_v = cn;
            const float hv = go * (2.f * sigm(2.f * cn) - 1.f);
            oa_v += hv * woutS[(bn * BS + s) * 256 + usel];
            hT[hw_base + (((tc + 1) & 1) << 9)] = (short)f2bf(hv);
            if (t0 + C_T < T_SZ && tc == C_T - 1 && valid)
                h_st[(size_t)(b0 + bsel) * H_SZ + usel] = hv;

            if (s == BS - 1)
                __syncthreads();          // block boundary: drain vmcnt too
            else
                asm volatile("s_waitcnt lgkmcnt(0)\n\ts_barrier" ::: "memory");
        }
    }

    if (t0 + C_T >= T_SZ) {
        float v = valid ? oa_v : 0.f;
        // lane bit3 = batch; sum over bits 0,1,2,4,5
        v += __shfl_xor(v, 1);
        v += __shfl_xor(v, 2);
        v += __shfl_xor(v, 4);
        v += __shfl_xor(v, 16);
        v += __shfl_xor(v, 32);
        if (lane == 0) redbuf[wv * 2]     = v;
        if (lane == 8) redbuf[wv * 2 + 1] = v;
        __syncthreads();
        if (tid < 2) {
            float r = bout[0];
            #pragma unroll
            for (int w = 0; w < 8; ++w) r += redbuf[w * 2 + tid];
            out[b0 + tid] = r;
        }
    } else if (valid) {
        c_st [(size_t)(b0 + bsel) * H_SZ + usel] = c_v;
        oa_st[(size_t)(b0 + bsel) * H_SZ + usel] = oa_v;
    }
}

// ---------------------------------------------------------------------------
extern "C" void kernel_launch(void* const* d_in, const int* in_sizes, int n_in,
                              void* d_out, int out_size, void* d_ws, size_t ws_size,
                              hipStream_t stream)
{
    const float* x    = (const float*)d_in[0];
    const float* Wih  = (const float*)d_in[1];
    const float* Whh  = (const float*)d_in[2];
    const float* bih  = (const float*)d_in[3];
    const float* bhh  = (const float*)d_in[4];
    const float* Wout = (const float*)d_in[5];
    const float* bout = (const float*)d_in[6];
    float* out = (float*)d_out;

    // ws layout: state | bsum | wpad | xbf | wbf | pre
    char* ws = (char*)d_ws;
    float* state = (float*)ws;
    size_t off = (size_t)3 * B_SZ * H_SZ * sizeof(float);
    float* bsum = (float*)(ws + off);
    off += (size_t)G4 * sizeof(float);
    float* wpad = (float*)(ws + off);
    off += (size_t)(T_SZ * H_SZ + 256) * sizeof(float);
    unsigned short* xbf = (unsigned short*)(ws + off);
    off += (size_t)B_SZ * T_SZ * D_SZ * 2;
    unsigned short* wbf = (unsigned short*)(ws + off);
    off += (size_t)G4 * D_SZ * 2;
    unsigned short* pre = (unsigned short*)(ws + off);

    const size_t per_t = (size_t)NSUB * 4 * 512 * 4 * 2;   // 819,200 B per step
    int ct = 512;
    while (ct > BS && off + (size_t)ct * per_t > ws_size) ct >>= 1;

    cvt_bf16<<<dim3(2048), dim3(256), 0, stream>>>(x, xbf, B_SZ * T_SZ * D_SZ / 4);
    cvt_w_perm<<<dim3(200), dim3(256), 0, stream>>>(Wih, wbf);
    prep<<<dim3(402), dim3(256), 0, stream>>>(bih, bhh, Wout, bsum, wpad);

    for (int t0 = 0; t0 < T_SZ; t0 += ct) {
        pre_gemm<<<dim3(ct, 8, 4), dim3(256), 0, stream>>>(
            xbf, wbf, bsum, pre, t0);
        lstm_rec<<<dim3(256), dim3(512), 0, stream>>>(
            pre, Whh, wpad, bout, state, out, t0, ct);
    }
}

// Round 4
// 1667.495 us; speedup vs baseline: 1.0025x; 1.0025x over previous
//
#include <hip/hip_runtime.h>
#include <hip/hip_bf16.h>

#define B_SZ 512
#define T_SZ 512
#define D_SZ 256
#define H_SZ 200
#define G4   800   // 4*H
#define NSUB 50    // gate subtiles of 16
#define BS   8     // steps per LDS staging block
#define WROW 800   // bytes per Wout row (200 floats)

typedef __attribute__((ext_vector_type(8))) short short8;
typedef __attribute__((ext_vector_type(4))) short short4v;
typedef __attribute__((ext_vector_type(4))) float f32x4;

__device__ __forceinline__ unsigned short f2bf(float x) {
    unsigned u = __builtin_bit_cast(unsigned, x);
    unsigned r = (u + 0x7FFFu + ((u >> 16) & 1u)) >> 16;
    return (unsigned short)r;
}
__device__ __forceinline__ float sigm(float v) { return 1.f / (1.f + __expf(-v)); }

__device__ __forceinline__ void gl_lds16(const void* g, void* l) {
    __builtin_amdgcn_global_load_lds(
        (const __attribute__((address_space(1))) unsigned int*)g,
        (__attribute__((address_space(3))) unsigned int*)l, 16, 0, 0);
}

// ---------------------------------------------------------------------------
// Kernel 0: fp32 -> bf16 conversion (x)
// ---------------------------------------------------------------------------
__global__ __launch_bounds__(256)
void cvt_bf16(const float* __restrict__ src, unsigned short* __restrict__ dst, int n4)
{
    int i = blockIdx.x * 256 + threadIdx.x;
    const int stride = gridDim.x * 256;
    for (; i < n4; i += stride) {
        float4 v = ((const float4*)src)[i];
        unsigned a = (unsigned)f2bf(v.x) | ((unsigned)f2bf(v.y) << 16);
        unsigned b = (unsigned)f2bf(v.z) | ((unsigned)f2bf(v.w) << 16);
        ((uint2*)dst)[i] = make_uint2(a, b);
    }
}

// ---------------------------------------------------------------------------
// Kernel 0b: W_ih fp32 -> bf16 with gate-row interleave.
// New row r = unit*4 + gate  sources old row  (r&3)*200 + (r>>2).
// ---------------------------------------------------------------------------
__global__ __launch_bounds__(256)
void cvt_w_perm(const float* __restrict__ Wih, unsigned short* __restrict__ dst)
{
    int i = blockIdx.x * 256 + threadIdx.x;     // over 800*64 float4 chunks
    if (i >= G4 * (D_SZ / 4)) return;
    const int r = i >> 6, ch = i & 63;
    const int p = (r & 3) * H_SZ + (r >> 2);
    float4 v = ((const float4*)(Wih + (size_t)p * D_SZ))[ch];
    unsigned a = (unsigned)f2bf(v.x) | ((unsigned)f2bf(v.y) << 16);
    unsigned b = (unsigned)f2bf(v.z) | ((unsigned)f2bf(v.w) << 16);
    ((uint2*)dst)[i] = make_uint2(a, b);
}

// ---------------------------------------------------------------------------
// Kernel 0c: permuted bias sum (b_ih+b_hh) + padded Wout copy.
// ---------------------------------------------------------------------------
__global__ __launch_bounds__(256)
void prep(const float* __restrict__ bih, const float* __restrict__ bhh,
          const float* __restrict__ Wout, float* __restrict__ bsum,
          float* __restrict__ wpad)
{
    const int i = blockIdx.x * 256 + threadIdx.x;
    if (i < G4) {
        const int p = (i & 3) * H_SZ + (i >> 2);
        bsum[i] = bih[p] + bhh[p];
    }
    if (i < T_SZ * H_SZ + 256)
        wpad[i] = (i < T_SZ * H_SZ) ? Wout[i] : 0.f;
}

// ---------------------------------------------------------------------------
// Kernel 1: pre = x@W_ih^T + bsum, bf16 MFMA (rows already gate-interleaved)
// Round 4: 256x128 tile, 512 threads (8 waves as 4 gate-quarters x 2 batch
// halves, acc 4x4 per wave).  2x MFMA per barrier pair vs round 2; half WGs.
// output layout pre[tt][S(50)][q(4)][b(512)][i(4)] bf16  (g = S*16 + q*4 + i)
// ---------------------------------------------------------------------------
__global__ __launch_bounds__(512)
void pre_gemm(const unsigned short* __restrict__ xbf,
              const unsigned short* __restrict__ wbf,
              const float* __restrict__ bs,
              unsigned short* __restrict__ pre, int t0)
{
    const int tt = blockIdx.x;
    const int t  = t0 + tt;
    const int b0 = blockIdx.y * 128;
    const int g0 = blockIdx.z * 256;

    __shared__ unsigned short Al[256 * 32];   // 16 KB
    __shared__ unsigned short Bl[128 * 32];   //  8 KB

    const int tid  = threadIdx.x;
    const int wv   = tid >> 6;
    const int lane = tid & 63;
    const int col  = lane & 15, q = lane >> 4;
    const int wm   = wv >> 1;      // gate quarter (64 rows)
    const int wn   = wv & 1;       // batch half  (64 cols)

    f32x4 acc[4][4];
    #pragma unroll
    for (int i = 0; i < 4; ++i)
        #pragma unroll
        for (int j = 0; j < 4; ++j) acc[i][j] = (f32x4)0.f;

    const int arow_l = lane >> 2;          // 0..15
    const int akoff  = (lane & 3) * 8;

    for (int kc = 0; kc < 8; ++kc) {
        const int d0 = kc * 32;
        if (kc) __syncthreads();
        // A: 256 rows = 8 waves x 2 loads x 16 rows
        #pragma unroll
        for (int j = 0; j < 2; ++j) {
            int g = g0 + wv * 32 + j * 16 + arow_l;
            if (g > G4 - 1) g = G4 - 1;
            gl_lds16(wbf + (size_t)g * D_SZ + d0 + akoff,
                     (void*)(Al + (wv * 32 + j * 16) * 32));
        }
        // B: 128 rows = 8 waves x 1 load x 16 rows
        {
            const int brow = b0 + wv * 16 + arow_l;
            gl_lds16(xbf + ((size_t)brow * T_SZ + t) * D_SZ + d0 + akoff,
                     (void*)(Bl + (wv * 16) * 32));
        }
        __syncthreads();

        short8 af[4], bv[4];
        #pragma unroll
        for (int s = 0; s < 4; ++s)
            af[s] = *(const short8*)&Al[(wm * 64 + s * 16 + col) * 32 + q * 8];
        #pragma unroll
        for (int s = 0; s < 4; ++s)
            bv[s] = *(const short8*)&Bl[(wn * 64 + s * 16 + col) * 32 + q * 8];
        #pragma unroll
        for (int gs = 0; gs < 4; ++gs)
            #pragma unroll
            for (int bsi = 0; bsi < 4; ++bsi)
                acc[gs][bsi] = __builtin_amdgcn_mfma_f32_16x16x32_bf16(af[gs], bv[bsi], acc[gs][bsi], 0, 0, 0);
    }

    #pragma unroll
    for (int gs = 0; gs < 4; ++gs) {
        const int S = blockIdx.z * 16 + wm * 4 + gs;
        if (S < NSUB) {
            const int gq = S * 16 + q * 4;
            const float4 bi = *(const float4*)&bs[gq];
            #pragma unroll
            for (int bsi = 0; bsi < 4; ++bsi) {
                f32x4 a = acc[gs][bsi];
                unsigned lo = (unsigned)f2bf(a[0] + bi.x) |
                              ((unsigned)f2bf(a[1] + bi.y) << 16);
                unsigned hi = (unsigned)f2bf(a[2] + bi.z) |
                              ((unsigned)f2bf(a[3] + bi.w) << 16);
                const size_t idx = (((size_t)tt * NSUB + S) * 4 + q) * 512 +
                                   (b0 + wn * 64 + bsi * 16 + col);
                ((uint2*)pre)[idx] = make_uint2(lo, hi);
            }
        }
    }
}

// ---------------------------------------------------------------------------
// Kernel 2: LSTM recurrence. 256 WGs x 512 thr (8 waves); 2 batches per WG.
// Round-2 structure (7 reg tiles/wave, in-register elementwise, dedup'd
// ownership) + round-4 scheduling:
//  - Wout rows staged per BLOCK (wave wv stages row blk*8+wv) -> no per-step
//    global_load_lds / vmcnt traffic.
//  - steps 0..6 of each block use an lgkmcnt-only barrier (staging loads for
//    the next block stay in flight); full __syncthreads() only at step 7.
//  - next step's pre-acc (7x b64) and Wout scalar are PREFETCHED into regs
//    before the barrier, so the post-barrier critical path is ds_read(h)->MFMA.
// ---------------------------------------------------------------------------
__global__ __launch_bounds__(512, 2)
void lstm_rec(const unsigned short* __restrict__ pre,  // [ct][50][4][512][4] bf16 (permuted rows)
              const float* __restrict__ Whh,           // original [4H][H] fp32
              const float* __restrict__ wpad,          // padded Wout copy [512*200 + 256]
              const float* __restrict__ bout,
              float* __restrict__ state,               // h,c,oa each [512][200]
              float* __restrict__ out,
              int t0, int C_T)
{
    const int bk = blockIdx.x;
    const int cidx = (bk >> 3) + (bk & 7) * 32;   // XCD swizzle
    const int b0 = cidx * 2;

    const int tid = threadIdx.x, lane = tid & 63, wv = tid >> 6;
    const int col = lane & 15, q = lane >> 4;

    __shared__ __align__(16) unsigned short preS[2 * BS * 1600]; // 51.2 KB
    // hT: buf0 rows at [0,512), buf1 at [512,1024), scrap [1024,1600)
    __shared__ __align__(16) short hT[1600];                     // 3.2 KB
    __shared__ __align__(16) float woutS[2 * BS * 256];          // 16.4 KB
    __shared__ float redbuf[16];

    // tiles: waves 0,1 -> 7 real; waves 2..7 -> 6 real + 1 redundant/dummy
    const int tbase = (wv < 2) ? wv * 7 : 14 + (wv - 2) * 6;

    int pofs[7], tjv[7];
    #pragma unroll
    for (int j = 0; j < 7; ++j) {
        const int tr = tbase + j;
        const int tj = tr > 49 ? 49 : tr;
        tjv[j] = tj;
        pofs[j] = (tj * 4 + q) * 8 + (col >> 3) * 4;   // shorts, within step slab
    }
    const int c7 = col & 7;
    const int jsel = (c7 < 7) ? c7 : 6;                  // tile this lane finishes
    // dedup: waves 0,1 own 7 tiles; waves 2..7 own 6 (their j=6 duplicates
    // the next wave's j=0 and must NOT be accumulated into the output)
    const bool valid = (wv < 2) ? (c7 < 7) : (c7 < 6);
    const int bsel = col >> 3;                           // batch this lane finishes
    const int usel = tjv[jsel] * 4 + q;                  // hidden unit
    const int hw_base = valid ? (bsel * 256 + usel) : (1024 + lane);
    const int rbase = bsel * 256;                        // B-operand read base

    // ---- W_hh fragments (bf16), rows permuted; K padded 6x32 + 16 tail ----
    short8 aw[7][6];
#if __has_builtin(__builtin_amdgcn_mfma_f32_16x16x16bf16_1k)
    short4v aw6[7];
#else
    short8 aw6[7];
#endif
    #pragma unroll
    for (int j = 0; j < 7; ++j) {
        const int gp = tjv[j] * 16 + col;                       // permuted row
        const float* wr = Whh + (size_t)((gp & 3) * H_SZ + (gp >> 2)) * H_SZ;
        #pragma unroll
        for (int kc = 0; kc < 6; ++kc) {
            const int k = kc * 32 + q * 8;
            float4 f0 = *(const float4*)(wr + k);
            float4 f1 = *(const float4*)(wr + k + 4);
            short8 s;
            s[0] = (short)f2bf(f0.x); s[1] = (short)f2bf(f0.y);
            s[2] = (short)f2bf(f0.z); s[3] = (short)f2bf(f0.w);
            s[4] = (short)f2bf(f1.x); s[5] = (short)f2bf(f1.y);
            s[6] = (short)f2bf(f1.z); s[7] = (short)f2bf(f1.w);
            aw[j][kc] = s;
        }
#if __has_builtin(__builtin_amdgcn_mfma_f32_16x16x16bf16_1k)
        short4v t4 = (short4v)0;
        if (q < 2) {
            float4 f = *(const float4*)(wr + 192 + q * 4);
            t4[0] = (short)f2bf(f.x); t4[1] = (short)f2bf(f.y);
            t4[2] = (short)f2bf(f.z); t4[3] = (short)f2bf(f.w);
        }
        aw6[j] = t4;
#else
        short8 t8 = (short8)0;
        if (q == 0) {
            float4 f0 = *(const float4*)(wr + 192);
            float4 f1 = *(const float4*)(wr + 196);
            t8[0] = (short)f2bf(f0.x); t8[1] = (short)f2bf(f0.y);
            t8[2] = (short)f2bf(f0.z); t8[3] = (short)f2bf(f0.w);
            t8[4] = (short)f2bf(f1.x); t8[5] = (short)f2bf(f1.y);
            t8[6] = (short)f2bf(f1.z); t8[7] = (short)f2bf(f1.w);
        }
        aw6[j] = t8;
#endif
    }

    float* h_st  = state;
    float* c_st  = state + (size_t)B_SZ * H_SZ;
    float* oa_st = state + (size_t)2 * B_SZ * H_SZ;

    // ---- init hT (buf0 = h state or zeros; buf1 + scrap + k>=200 zeros) ----
    for (int i = tid; i < 1600; i += 512) {
        short v = 0;
        if (t0 > 0 && i < 512) {
            const int r = i >> 8, u = i & 255;
            if (u < H_SZ) v = (short)f2bf(h_st[(size_t)(b0 + r) * H_SZ + u]);
        }
        hT[i] = v;
    }

    // ---- per-lane cell state (scalar: one (unit,batch) per lane) ----
    float c_v = 0.f, oa_v = 0.f;
    if (t0 > 0 && valid) {
        c_v  = c_st [(size_t)(b0 + bsel) * H_SZ + usel];
        oa_v = oa_st[(size_t)(b0 + bsel) * H_SZ + usel];
    }

    const int nblk = C_T / BS;
    const char* preb = (const char*)pre;

    // ---- stage block 0 (pre slabs + Wout rows t0..t0+7) ----
    {
        const char* src = preb + ((size_t)wv * 200) * 4096 + (size_t)b0 * 8;
        unsigned short* dst = preS + (0 * BS + wv) * 1600;
        gl_lds16(src + (size_t)lane * 4096,         dst);
        gl_lds16(src + (size_t)(lane + 64) * 4096,  dst + 512);
        gl_lds16(src + (size_t)(lane + 128) * 4096, dst + 1024);
        gl_lds16(src + (size_t)(lane + 136) * 4096, dst + 1088);
        gl_lds16((const char*)wpad + (size_t)(t0 + wv) * WROW + lane * 16,
                 (void*)(woutS + wv * 256));
    }
    __syncthreads();

    for (int blk = 0; blk < nblk; ++blk) {
        const int bn = blk & 1;
        // stage next block (clamped) into other buffers
        {
            const int nb = (blk + 1 < nblk) ? blk + 1 : blk;
            const char* src = preb + ((size_t)(nb * BS + wv) * 200) * 4096 + (size_t)b0 * 8;
            unsigned short* dst = preS + ((bn ^ 1) * BS + wv) * 1600;
            gl_lds16(src + (size_t)lane * 4096,         dst);
            gl_lds16(src + (size_t)(lane + 64) * 4096,  dst + 512);
            gl_lds16(src + (size_t)(lane + 128) * 4096, dst + 1024);
            gl_lds16(src + (size_t)(lane + 136) * 4096, dst + 1088);
            gl_lds16((const char*)wpad + (size_t)(t0 + nb * BS + wv) * WROW + lane * 16,
                     (void*)(woutS + ((bn ^ 1) * BS + wv) * 256));
        }
        const unsigned short* psb = preS + bn * (BS * 1600);

        // operand regs for step 0 of this block (data synced at prior barrier)
        uint2 pr[7];
        #pragma unroll
        for (int j = 0; j < 7; ++j)
            pr[j] = *(const uint2*)(psb + pofs[j]);
        float wout_c = woutS[(bn * BS) * 256 + usel];

        #pragma unroll
        for (int s = 0; s < BS; ++s) {
            const int tc = blk * BS + s;
            const short* hrow = hT + ((tc & 1) << 9) + rbase;

            // acc init from prefetched pre regs (bf16 -> f32)
            f32x4 acc[7];
            #pragma unroll
            for (int j = 0; j < 7; ++j) {
                f32x4 a;
                a[0] = __builtin_bit_cast(float, pr[j].x << 16);
                a[1] = __builtin_bit_cast(float, pr[j].x & 0xFFFF0000u);
                a[2] = __builtin_bit_cast(float, pr[j].y << 16);
                a[3] = __builtin_bit_cast(float, pr[j].y & 0xFFFF0000u);
                acc[j] = a;
            }
            // MFMA: acc += Whh * h  (h replicated per batch-half; broadcast reads)
            #pragma unroll
            for (int kc = 0; kc < 6; ++kc) {
                const short8 bf = *(const short8*)(hrow + kc * 32 + q * 8);
                #pragma unroll
                for (int j = 0; j < 7; ++j)
                    acc[j] = __builtin_amdgcn_mfma_f32_16x16x32_bf16(aw[j][kc], bf, acc[j], 0, 0, 0);
            }
#if __has_builtin(__builtin_amdgcn_mfma_f32_16x16x16bf16_1k)
            {
                const short4v bt = *(const short4v*)(hrow + 192 + q * 4);
                #pragma unroll
                for (int j = 0; j < 7; ++j)
                    acc[j] = __builtin_amdgcn_mfma_f32_16x16x16bf16_1k(aw6[j], bt, acc[j], 0, 0, 0);
            }
#else
            {
                const short8 bt = *(const short8*)(hrow + 192 + q * 8);
                #pragma unroll
                for (int j = 0; j < 7; ++j)
                    acc[j] = __builtin_amdgcn_mfma_f32_16x16x32_bf16(aw6[j], bt, acc[j], 0, 0, 0);
            }
#endif
            // in-register elementwise: this lane finishes tile jsel
            f32x4 sel = acc[0];
            #pragma unroll
            for (int j = 1; j < 7; ++j)
                if (jsel == j) sel = acc[j];

            const float gi = sigm(sel[0]);
            const float gf = sigm(sel[1]);
            const float gg = 2.f * sigm(2.f * sel[2]) - 1.f;
            const float go = sigm(sel[3]);
            const float cn = gf * c_v + gi * gg;
            c_v = cn;
            const float hv = go * (2.f * sigm(2.f * cn) - 1.f);
            oa_v += hv * wout_c;
            hT[hw_base + (((tc + 1) & 1) << 9)] = (short)f2bf(hv);
            if (t0 + C_T < T_SZ && tc == C_T - 1 && valid)
                h_st[(size_t)(b0 + bsel) * H_SZ + usel] = hv;

            if (s < BS - 1) {
                // prefetch next step's operands (same buffer, already staged)
                #pragma unroll
                for (int j = 0; j < 7; ++j)
                    pr[j] = *(const uint2*)(psb + (s + 1) * 1600 + pofs[j]);
                wout_c = woutS[(bn * BS + s + 1) * 256 + usel];
                // lgkm-only barrier: h-write + prefetch drained; staging
                // loads for the NEXT block stay in flight.
                asm volatile("s_waitcnt lgkmcnt(0)\n\ts_barrier" ::: "memory");
            } else {
                __syncthreads();          // block boundary: drain vmcnt too
            }
        }
    }

    if (t0 + C_T >= T_SZ) {
        float v = valid ? oa_v : 0.f;
        // lane bit3 = batch; sum over bits 0,1,2,4,5
        v += __shfl_xor(v, 1);
        v += __shfl_xor(v, 2);
        v += __shfl_xor(v, 4);
        v += __shfl_xor(v, 16);
        v += __shfl_xor(v, 32);
        if (lane == 0) redbuf[wv * 2]     = v;
        if (lane == 8) redbuf[wv * 2 + 1] = v;
        __syncthreads();
        if (tid < 2) {
            float r = bout[0];
            #pragma unroll
            for (int w = 0; w < 8; ++w) r += redbuf[w * 2 + tid];
            out[b0 + tid] = r;
        }
    } else if (valid) {
        c_st [(size_t)(b0 + bsel) * H_SZ + usel] = c_v;
        oa_st[(size_t)(b0 + bsel) * H_SZ + usel] = oa_v;
    }
}

// ---------------------------------------------------------------------------
extern "C" void kernel_launch(void* const* d_in, const int* in_sizes, int n_in,
                              void* d_out, int out_size, void* d_ws, size_t ws_size,
                              hipStream_t stream)
{
    const float* x    = (const float*)d_in[0];
    const float* Wih  = (const float*)d_in[1];
    const float* Whh  = (const float*)d_in[2];
    const float* bih  = (const float*)d_in[3];
    const float* bhh  = (const float*)d_in[4];
    const float* Wout = (const float*)d_in[5];
    const float* bout = (const float*)d_in[6];
    float* out = (float*)d_out;

    // ws layout: state | bsum | wpad | xbf | wbf | pre
    char* ws = (char*)d_ws;
    float* state = (float*)ws;
    size_t off = (size_t)3 * B_SZ * H_SZ * sizeof(float);
    float* bsum = (float*)(ws + off);
    off += (size_t)G4 * sizeof(float);
    float* wpad = (float*)(ws + off);
    off += (size_t)(T_SZ * H_SZ + 256) * sizeof(float);
    unsigned short* xbf = (unsigned short*)(ws + off);
    off += (size_t)B_SZ * T_SZ * D_SZ * 2;
    unsigned short* wbf = (unsigned short*)(ws + off);
    off += (size_t)G4 * D_SZ * 2;
    unsigned short* pre = (unsigned short*)(ws + off);

    const size_t per_t = (size_t)NSUB * 4 * 512 * 4 * 2;   // 819,200 B per step
    int ct = 512;
    while (ct > BS && off + (size_t)ct * per_t > ws_size) ct >>= 1;

    cvt_bf16<<<dim3(2048), dim3(256), 0, stream>>>(x, xbf, B_SZ * T_SZ * D_SZ / 4);
    cvt_w_perm<<<dim3(200), dim3(256), 0, stream>>>(Wih, wbf);
    prep<<<dim3(402), dim3(256), 0, stream>>>(bih, bhh, Wout, bsum, wpad);

    for (int t0 = 0; t0 < T_SZ; t0 += ct) {
        pre_gemm<<<dim3(ct, 4, 4), dim3(512), 0, stream>>>(
            xbf, wbf, bsum, pre, t0);
        lstm_rec<<<dim3(256), dim3(512), 0, stream>>>(
            pre, Whh, wpad, bout, state, out, t0, ct);
    }
}

// Round 5
// 1618.781 us; speedup vs baseline: 1.0327x; 1.0301x over previous
//
#include <hip/hip_runtime.h>
#include <hip/hip_bf16.h>

#define B_SZ 512
#define T_SZ 512
#define D_SZ 256
#define H_SZ 200
#define G4   800   // 4*H
#define NSUB 50    // gate subtiles of 16
#define BS   8     // steps per LDS staging block
#define WROW 800   // bytes per Wout row (200 floats)

typedef __attribute__((ext_vector_type(8))) short short8;
typedef __attribute__((ext_vector_type(4))) short short4v;
typedef __attribute__((ext_vector_type(4))) float f32x4;

#if __has_builtin(__builtin_amdgcn_mfma_f32_16x16x16bf16_1k)
#define HAS_1K 1
typedef short4v aw6_t;
#else
#define HAS_1K 0
typedef short8 aw6_t;
#endif

__device__ __forceinline__ unsigned short f2bf(float x) {
    unsigned u = __builtin_bit_cast(unsigned, x);
    unsigned r = (u + 0x7FFFu + ((u >> 16) & 1u)) >> 16;
    return (unsigned short)r;
}
__device__ __forceinline__ float sigm(float v) { return 1.f / (1.f + __expf(-v)); }

__device__ __forceinline__ void gl_lds16(const void* g, void* l) {
    __builtin_amdgcn_global_load_lds(
        (const __attribute__((address_space(1))) unsigned int*)g,
        (__attribute__((address_space(3))) unsigned int*)l, 16, 0, 0);
}

// ---------------------------------------------------------------------------
// Kernel 0: fp32 -> bf16 conversion (x)
// ---------------------------------------------------------------------------
__global__ __launch_bounds__(256)
void cvt_bf16(const float* __restrict__ src, unsigned short* __restrict__ dst, int n4)
{
    int i = blockIdx.x * 256 + threadIdx.x;
    const int stride = gridDim.x * 256;
    for (; i < n4; i += stride) {
        float4 v = ((const float4*)src)[i];
        unsigned a = (unsigned)f2bf(v.x) | ((unsigned)f2bf(v.y) << 16);
        unsigned b = (unsigned)f2bf(v.z) | ((unsigned)f2bf(v.w) << 16);
        ((uint2*)dst)[i] = make_uint2(a, b);
    }
}

// ---------------------------------------------------------------------------
// Kernel 0b: W_ih fp32 -> bf16 with gate-row interleave.
// New row r = unit*4 + gate  sources old row  (r&3)*200 + (r>>2).
// ---------------------------------------------------------------------------
__global__ __launch_bounds__(256)
void cvt_w_perm(const float* __restrict__ Wih, unsigned short* __restrict__ dst)
{
    int i = blockIdx.x * 256 + threadIdx.x;     // over 800*64 float4 chunks
    if (i >= G4 * (D_SZ / 4)) return;
    const int r = i >> 6, ch = i & 63;
    const int p = (r & 3) * H_SZ + (r >> 2);
    float4 v = ((const float4*)(Wih + (size_t)p * D_SZ))[ch];
    unsigned a = (unsigned)f2bf(v.x) | ((unsigned)f2bf(v.y) << 16);
    unsigned b = (unsigned)f2bf(v.z) | ((unsigned)f2bf(v.w) << 16);
    ((uint2*)dst)[i] = make_uint2(a, b);
}

// ---------------------------------------------------------------------------
// Kernel 0c: permuted bias sum (b_ih+b_hh) + padded Wout copy.
// ---------------------------------------------------------------------------
__global__ __launch_bounds__(256)
void prep(const float* __restrict__ bih, const float* __restrict__ bhh,
          const float* __restrict__ Wout, float* __restrict__ bsum,
          float* __restrict__ wpad)
{
    const int i = blockIdx.x * 256 + threadIdx.x;
    if (i < G4) {
        const int p = (i & 3) * H_SZ + (i >> 2);
        bsum[i] = bih[p] + bhh[p];
    }
    if (i < T_SZ * H_SZ + 256)
        wpad[i] = (i < T_SZ * H_SZ) ? Wout[i] : 0.f;
}

// ---------------------------------------------------------------------------
// Kernel 1: pre = x@W_ih^T + bsum, bf16 MFMA (rows already gate-interleaved)
// Round 5: M-tile 128 x N-tile 128, z=7 (896 rows for G4=800 -> 10.7% waste
// vs 22% with 256-row tiles).  256 thr / 4 waves (2 gate-halves x 2 batch
// halves), acc 4x4 per wave.
// output layout pre[tt][S(50)][q(4)][b(512)][i(4)] bf16  (g = S*16 + q*4 + i)
// ---------------------------------------------------------------------------
__global__ __launch_bounds__(256)
void pre_gemm(const unsigned short* __restrict__ xbf,
              const unsigned short* __restrict__ wbf,
              const float* __restrict__ bs,
              unsigned short* __restrict__ pre, int t0)
{
    const int tt = blockIdx.x;
    const int t  = t0 + tt;
    const int b0 = blockIdx.y * 128;
    const int g0 = blockIdx.z * 128;

    __shared__ unsigned short Al[128 * 32];   // 8 KB
    __shared__ unsigned short Bl[128 * 32];   // 8 KB

    const int tid  = threadIdx.x;
    const int wv   = tid >> 6;
    const int lane = tid & 63;
    const int col  = lane & 15, q = lane >> 4;
    const int wm   = wv >> 1;      // gate half (64 rows)
    const int wn   = wv & 1;       // batch half (64 cols)

    f32x4 acc[4][4];
    #pragma unroll
    for (int i = 0; i < 4; ++i)
        #pragma unroll
        for (int j = 0; j < 4; ++j) acc[i][j] = (f32x4)0.f;

    const int arow_l = lane >> 2;          // 0..15
    const int akoff  = (lane & 3) * 8;

    for (int kc = 0; kc < 8; ++kc) {
        const int d0 = kc * 32;
        if (kc) __syncthreads();
        // A: 128 rows = 4 waves x 2 loads x 16 rows
        #pragma unroll
        for (int j = 0; j < 2; ++j) {
            int g = g0 + wv * 32 + j * 16 + arow_l;
            if (g > G4 - 1) g = G4 - 1;
            gl_lds16(wbf + (size_t)g * D_SZ + d0 + akoff,
                     (void*)(Al + (wv * 32 + j * 16) * 32));
        }
        // B: 128 rows = 4 waves x 2 loads x 16 rows
        #pragma unroll
        for (int j = 0; j < 2; ++j) {
            const int brow = b0 + wv * 32 + j * 16 + arow_l;
            gl_lds16(xbf + ((size_t)brow * T_SZ + t) * D_SZ + d0 + akoff,
                     (void*)(Bl + (wv * 32 + j * 16) * 32));
        }
        __syncthreads();

        short8 af[4], bv[4];
        #pragma unroll
        for (int s = 0; s < 4; ++s)
            af[s] = *(const short8*)&Al[(wm * 64 + s * 16 + col) * 32 + q * 8];
        #pragma unroll
        for (int s = 0; s < 4; ++s)
            bv[s] = *(const short8*)&Bl[(wn * 64 + s * 16 + col) * 32 + q * 8];
        #pragma unroll
        for (int gs = 0; gs < 4; ++gs)
            #pragma unroll
            for (int bsi = 0; bsi < 4; ++bsi)
                acc[gs][bsi] = __builtin_amdgcn_mfma_f32_16x16x32_bf16(af[gs], bv[bsi], acc[gs][bsi], 0, 0, 0);
    }

    #pragma unroll
    for (int gs = 0; gs < 4; ++gs) {
        const int S = blockIdx.z * 8 + wm * 4 + gs;
        if (S < NSUB) {
            const int gq = S * 16 + q * 4;
            const float4 bi = *(const float4*)&bs[gq];
            #pragma unroll
            for (int bsi = 0; bsi < 4; ++bsi) {
                f32x4 a = acc[gs][bsi];
                unsigned lo = (unsigned)f2bf(a[0] + bi.x) |
                              ((unsigned)f2bf(a[1] + bi.y) << 16);
                unsigned hi = (unsigned)f2bf(a[2] + bi.z) |
                              ((unsigned)f2bf(a[3] + bi.w) << 16);
                const size_t idx = (((size_t)tt * NSUB + S) * 4 + q) * 512 +
                                   (b0 + wn * 64 + bsi * 16 + col);
                ((uint2*)pre)[idx] = make_uint2(lo, hi);
            }
        }
    }
}

// ---------------------------------------------------------------------------
// One LSTM recurrence step for NT tiles: acc init from prefetched pre regs,
// Whh*h MFMA (6 x K32 + 1 x K16 tail per tile), select owned tile.
// ---------------------------------------------------------------------------
template<int NT>
__device__ __forceinline__ f32x4 lstm_step(
    const short8 (&aw)[7][6], const aw6_t (&aw6)[7],
    const uint2 (&pr)[7], const short* hrow, int jsel, int q)
{
    f32x4 acc[NT];
    #pragma unroll
    for (int j = 0; j < NT; ++j) {
        f32x4 a;
        a[0] = __builtin_bit_cast(float, pr[j].x << 16);
        a[1] = __builtin_bit_cast(float, pr[j].x & 0xFFFF0000u);
        a[2] = __builtin_bit_cast(float, pr[j].y << 16);
        a[3] = __builtin_bit_cast(float, pr[j].y & 0xFFFF0000u);
        acc[j] = a;
    }
    __builtin_amdgcn_s_setprio(1);
    #pragma unroll
    for (int kc = 0; kc < 6; ++kc) {
        const short8 bf = *(const short8*)(hrow + kc * 32 + q * 8);
        #pragma unroll
        for (int j = 0; j < NT; ++j)
            acc[j] = __builtin_amdgcn_mfma_f32_16x16x32_bf16(aw[j][kc], bf, acc[j], 0, 0, 0);
    }
#if HAS_1K
    {
        const short4v bt = *(const short4v*)(hrow + 192 + q * 4);
        #pragma unroll
        for (int j = 0; j < NT; ++j)
            acc[j] = __builtin_amdgcn_mfma_f32_16x16x16bf16_1k(aw6[j], bt, acc[j], 0, 0, 0);
    }
#else
    {
        const short8 bt = *(const short8*)(hrow + 192 + q * 8);
        #pragma unroll
        for (int j = 0; j < NT; ++j)
            acc[j] = __builtin_amdgcn_mfma_f32_16x16x32_bf16(aw6[j], bt, acc[j], 0, 0, 0);
    }
#endif
    __builtin_amdgcn_s_setprio(0);
    f32x4 sel = acc[0];
    #pragma unroll
    for (int j = 1; j < NT; ++j)
        if (jsel == j) sel = acc[j];
    return sel;
}

// ---------------------------------------------------------------------------
// Kernel 2: LSTM recurrence. 256 WGs x 512 thr (8 waves); 2 batches per WG.
// Round 5: EXACT tile cover, no redundant MFMA work.  Wave wv owns tiles
// wv*6 .. wv*6+5; waves 0,1 additionally own tiles 48,49 as a 7th tile.
// One wave-uniform branch per step picks lstm_step<7> vs lstm_step<6>
// (straight-line template arms; waves 2-7 no longer burn 7 MFMAs on a
// dummy tile -> -11% MFMA issue).  Elementwise fully in-register; one
// barrier per step (lgkm-only except at 8-step staging block boundary).
// ---------------------------------------------------------------------------
__global__ __launch_bounds__(512, 2)
void lstm_rec(const unsigned short* __restrict__ pre,  // [ct][50][4][512][4] bf16 (permuted rows)
              const float* __restrict__ Whh,           // original [4H][H] fp32
              const float* __restrict__ wpad,          // padded Wout copy [512*200 + 256]
              const float* __restrict__ bout,
              float* __restrict__ state,               // h,c,oa each [512][200]
              float* __restrict__ out,
              int t0, int C_T)
{
    const int bk = blockIdx.x;
    const int cidx = (bk >> 3) + (bk & 7) * 32;   // XCD swizzle
    const int b0 = cidx * 2;

    const int tid = threadIdx.x, lane = tid & 63, wv = tid >> 6;
    const int col = lane & 15, q = lane >> 4;

    __shared__ __align__(16) unsigned short preS[2 * BS * 1600]; // 51.2 KB
    // hT: buf0 rows at [0,512), buf1 at [512,1024), scrap [1024,1600)
    __shared__ __align__(16) short hT[1600];                     // 3.2 KB
    __shared__ __align__(16) float woutS[2 * BS * 256];          // 16.4 KB
    __shared__ float redbuf[16];

    const int c7 = col & 7;
    const int bsel = col >> 3;                           // batch this lane finishes
    const int rbase = bsel * 256;                        // B-operand read base

    // exact ownership: c7<6 -> tile wv*6+c7; c7==6 && wv<2 -> tile 48+wv
    const int jsel = (c7 < 6) ? c7 : ((c7 == 6 && wv < 2) ? 6 : 0);
    const bool valid = (c7 < 6) || (c7 == 6 && wv < 2);
    const int otile = (jsel < 6) ? (wv * 6 + jsel) : (48 + wv);
    const int usel = otile * 4 + q;                      // hidden unit
    const int hw_base = valid ? (bsel * 256 + usel) : (1024 + lane);

    int pofs[7];
    #pragma unroll
    for (int j = 0; j < 6; ++j)
        pofs[j] = ((wv * 6 + j) * 4 + q) * 8 + bsel * 4;   // shorts, within step slab
    pofs[6] = ((48 + (wv & 1)) * 4 + q) * 8 + bsel * 4;

    // ---- W_hh fragments (bf16), rows permuted; K padded 6x32 + 16 tail ----
    short8 aw[7][6];
    aw6_t aw6[7];
    auto ld_aw = [&](int j, int tile) {
        const int gp = tile * 16 + col;                       // permuted row
        const float* wr = Whh + (size_t)((gp & 3) * H_SZ + (gp >> 2)) * H_SZ;
        #pragma unroll
        for (int kc = 0; kc < 6; ++kc) {
            const int k = kc * 32 + q * 8;
            float4 f0 = *(const float4*)(wr + k);
            float4 f1 = *(const float4*)(wr + k + 4);
            short8 s;
            s[0] = (short)f2bf(f0.x); s[1] = (short)f2bf(f0.y);
            s[2] = (short)f2bf(f0.z); s[3] = (short)f2bf(f0.w);
            s[4] = (short)f2bf(f1.x); s[5] = (short)f2bf(f1.y);
            s[6] = (short)f2bf(f1.z); s[7] = (short)f2bf(f1.w);
            aw[j][kc] = s;
        }
#if HAS_1K
        short4v t4 = (short4v)0;
        if (q < 2) {
            float4 f = *(const float4*)(wr + 192 + q * 4);
            t4[0] = (short)f2bf(f.x); t4[1] = (short)f2bf(f.y);
            t4[2] = (short)f2bf(f.z); t4[3] = (short)f2bf(f.w);
        }
        aw6[j] = t4;
#else
        short8 t8 = (short8)0;
        if (q == 0) {
            float4 f0 = *(const float4*)(wr + 192);
            float4 f1 = *(const float4*)(wr + 196);
            t8[0] = (short)f2bf(f0.x); t8[1] = (short)f2bf(f0.y);
            t8[2] = (short)f2bf(f0.z); t8[3] = (short)f2bf(f0.w);
            t8[4] = (short)f2bf(f1.x); t8[5] = (short)f2bf(f1.y);
            t8[6] = (short)f2bf(f1.z); t8[7] = (short)f2bf(f1.w);
        }
        aw6[j] = t8;
#endif
    };
    #pragma unroll
    for (int j = 0; j < 6; ++j) ld_aw(j, wv * 6 + j);
    if (wv < 2) ld_aw(6, 48 + wv);

    float* h_st  = state;
    float* c_st  = state + (size_t)B_SZ * H_SZ;
    float* oa_st = state + (size_t)2 * B_SZ * H_SZ;

    // ---- init hT (buf0 = h state or zeros; buf1 + scrap + k>=200 zeros) ----
    for (int i = tid; i < 1600; i += 512) {
        short v = 0;
        if (t0 > 0 && i < 512) {
            const int r = i >> 8, u = i & 255;
            if (u < H_SZ) v = (short)f2bf(h_st[(size_t)(b0 + r) * H_SZ + u]);
        }
        hT[i] = v;
    }

    // ---- per-lane cell state (scalar: one (unit,batch) per lane) ----
    float c_v = 0.f, oa_v = 0.f;
    if (t0 > 0 && valid) {
        c_v  = c_st [(size_t)(b0 + bsel) * H_SZ + usel];
        oa_v = oa_st[(size_t)(b0 + bsel) * H_SZ + usel];
    }

    const int nblk = C_T / BS;
    const char* preb = (const char*)pre;

    // ---- stage block 0 (pre slabs + Wout rows t0..t0+7) ----
    {
        const char* src = preb + ((size_t)wv * 200) * 4096 + (size_t)b0 * 8;
        unsigned short* dst = preS + (0 * BS + wv) * 1600;
        gl_lds16(src + (size_t)lane * 4096,         dst);
        gl_lds16(src + (size_t)(lane + 64) * 4096,  dst + 512);
        gl_lds16(src + (size_t)(lane + 128) * 4096, dst + 1024);
        gl_lds16(src + (size_t)(lane + 136) * 4096, dst + 1088);
        gl_lds16((const char*)wpad + (size_t)(t0 + wv) * WROW + lane * 16,
                 (void*)(woutS + wv * 256));
    }
    __syncthreads();

    for (int blk = 0; blk < nblk; ++blk) {
        const int bn = blk & 1;
        // stage next block (clamped) into other buffers
        {
            const int nb = (blk + 1 < nblk) ? blk + 1 : blk;
            const char* src = preb + ((size_t)(nb * BS + wv) * 200) * 4096 + (size_t)b0 * 8;
            unsigned short* dst = preS + ((bn ^ 1) * BS + wv) * 1600;
            gl_lds16(src + (size_t)lane * 4096,         dst);
            gl_lds16(src + (size_t)(lane + 64) * 4096,  dst + 512);
            gl_lds16(src + (size_t)(lane + 128) * 4096, dst + 1024);
            gl_lds16(src + (size_t)(lane + 136) * 4096, dst + 1088);
            gl_lds16((const char*)wpad + (size_t)(t0 + nb * BS + wv) * WROW + lane * 16,
                     (void*)(woutS + ((bn ^ 1) * BS + wv) * 256));
        }
        const unsigned short* psb = preS + bn * (BS * 1600);

        // operand regs for step 0 of this block (data synced at prior barrier)
        uint2 pr[7];
        #pragma unroll
        for (int j = 0; j < 7; ++j)
            pr[j] = *(const uint2*)(psb + pofs[j]);
        float wout_c = woutS[(bn * BS) * 256 + usel];

        #pragma unroll
        for (int s = 0; s < BS; ++s) {
            const int tc = blk * BS + s;
            const short* hrow = hT + ((tc & 1) << 9) + rbase;

            f32x4 sel;
            if (wv < 2) sel = lstm_step<7>(aw, aw6, pr, hrow, jsel, q);
            else        sel = lstm_step<6>(aw, aw6, pr, hrow, jsel, q);

            const float gi = sigm(sel[0]);
            const float gf = sigm(sel[1]);
            const float gg = 2.f * sigm(2.f * sel[2]) - 1.f;
            const float go = sigm(sel[3]);
            const float cn = gf * c_v + gi * gg;
            c_v = cn;
            const float hv = go * (2.f * sigm(2.f * cn) - 1.f);
            oa_v += hv * wout_c;
            hT[hw_base + (((tc + 1) & 1) << 9)] = (short)f2bf(hv);
            if (t0 + C_T < T_SZ && tc == C_T - 1 && valid)
                h_st[(size_t)(b0 + bsel) * H_SZ + usel] = hv;

            if (s < BS - 1) {
                // prefetch next step's operands (same buffer, already staged)
                #pragma unroll
                for (int j = 0; j < 7; ++j)
                    pr[j] = *(const uint2*)(psb + (s + 1) * 1600 + pofs[j]);
                wout_c = woutS[(bn * BS + s + 1) * 256 + usel];
                // lgkm-only barrier: h-write + prefetch drained; staging
                // loads for the NEXT block stay in flight.
                asm volatile("s_waitcnt lgkmcnt(0)\n\ts_barrier" ::: "memory");
            } else {
                __syncthreads();          // block boundary: drain vmcnt too
            }
        }
    }

    if (t0 + C_T >= T_SZ) {
        float v = valid ? oa_v : 0.f;
        // lane bit3 = batch; sum over bits 0,1,2,4,5
        v += __shfl_xor(v, 1);
        v += __shfl_xor(v, 2);
        v += __shfl_xor(v, 4);
        v += __shfl_xor(v, 16);
        v += __shfl_xor(v, 32);
        if (lane == 0) redbuf[wv * 2]     = v;
        if (lane == 8) redbuf[wv * 2 + 1] = v;
        __syncthreads();
        if (tid < 2) {
            float r = bout[0];
            #pragma unroll
            for (int w = 0; w < 8; ++w) r += redbuf[w * 2 + tid];
            out[b0 + tid] = r;
        }
    } else if (valid) {
        c_st [(size_t)(b0 + bsel) * H_SZ + usel] = c_v;
        oa_st[(size_t)(b0 + bsel) * H_SZ + usel] = oa_v;
    }
}

// ---------------------------------------------------------------------------
extern "C" void kernel_launch(void* const* d_in, const int* in_sizes, int n_in,
                              void* d_out, int out_size, void* d_ws, size_t ws_size,
                              hipStream_t stream)
{
    const float* x    = (const float*)d_in[0];
    const float* Wih  = (const float*)d_in[1];
    const float* Whh  = (const float*)d_in[2];
    const float* bih  = (const float*)d_in[3];
    const float* bhh  = (const float*)d_in[4];
    const float* Wout = (const float*)d_in[5];
    const float* bout = (const float*)d_in[6];
    float* out = (float*)d_out;

    // ws layout: state | bsum | wpad | xbf | wbf | pre
    char* ws = (char*)d_ws;
    float* state = (float*)ws;
    size_t off = (size_t)3 * B_SZ * H_SZ * sizeof(float);
    float* bsum = (float*)(ws + off);
    off += (size_t)G4 * sizeof(float);
    float* wpad = (float*)(ws + off);
    off += (size_t)(T_SZ * H_SZ + 256) * sizeof(float);
    unsigned short* xbf = (unsigned short*)(ws + off);
    off += (size_t)B_SZ * T_SZ * D_SZ * 2;
    unsigned short* wbf = (unsigned short*)(ws + off);
    off += (size_t)G4 * D_SZ * 2;
    unsigned short* pre = (unsigned short*)(ws + off);

    const size_t per_t = (size_t)NSUB * 4 * 512 * 4 * 2;   // 819,200 B per step
    int ct = 512;
    while (ct > BS && off + (size_t)ct * per_t > ws_size) ct >>= 1;

    cvt_bf16<<<dim3(2048), dim3(256), 0, stream>>>(x, xbf, B_SZ * T_SZ * D_SZ / 4);
    cvt_w_perm<<<dim3(200), dim3(256), 0, stream>>>(Wih, wbf);
    prep<<<dim3(402), dim3(256), 0, stream>>>(bih, bhh, Wout, bsum, wpad);

    for (int t0 = 0; t0 < T_SZ; t0 += ct) {
        pre_gemm<<<dim3(ct, 4, 7), dim3(256), 0, stream>>>(
            xbf, wbf, bsum, pre, t0);
        lstm_rec<<<dim3(256), dim3(512), 0, stream>>>(
            pre, Whh, wpad, bout, state, out, t0, ct);
    }
}